// Round 11
// baseline (2709.315 us; speedup 1.0000x reference)
//
#include <hip/hip_runtime.h>
#include <hip/hip_bf16.h>

#define B_   128
#define T_   512
#define L_   8
#define E_   128
#define H_   512

// Partition: 4 batch-groups (32 rows each) x 16 WGs = 64 WGs, 256 thr each.
// WG (bg,g): batch rows [bg*32,+32), hidden units [g*32,+32) -> 128 gate rows.
// Wave wv = gate type; per wave N=32 (2 N-tiles), M=32 (2 M-tiles), K=640.
// W fragments in registers, h slab staged in LDS per step.
//
// TAGGED-H EXCHANGE (R11): h stored as u32 = (step_tag) | (h_bf16 << 16).
// Producers just store (sc1, write-through to LLC) -- no drain, no flags.
// Consumers' fill loop IS the wait: load the slab, check embedded tags == t,
// retry until all match; on success the data is already in registers.
// Triple-buffered slots (reuse distance 3 > max WG drift 1); stale tags
// (t-3) and 0xAA poison (0xAAAA) never equal the expected tag.
#define BG_   4
#define WPG_  16
#define JW_   32
#define SLOTQ (B_ * H_ / 2)   // u64 per tagged-h slot (32768; 2 u32/u64)
#define GSTR  132             // gbuf row stride (floats)

typedef __attribute__((ext_vector_type(8))) short s8v;   // 8 bf16
typedef __attribute__((ext_vector_type(4))) float f4v;   // MFMA acc
typedef unsigned long long u64;

__device__ __forceinline__ float bf16u_to_f(unsigned short s) {
  union { unsigned u; float f; } c; c.u = ((unsigned)s) << 16; return c.f;
}
// LLC-coherent (sc1) accesses: bypass non-coherent per-XCD L2.
__device__ __forceinline__ u64 llc_load8(const void* p) {
  return __hip_atomic_load((const u64*)p, __ATOMIC_RELAXED, __HIP_MEMORY_SCOPE_AGENT);
}
__device__ __forceinline__ void llc_store8(void* p, u64 v) {
  __hip_atomic_store((u64*)p, v, __ATOMIC_RELAXED, __HIP_MEMORY_SCOPE_AGENT);
}
// Fast activations via v_exp_f32 + v_rcp_f32 (~1e-6 abs err)
__device__ __forceinline__ float sigf(float x) {
  return __builtin_amdgcn_rcpf(1.f + __expf(-x));
}
__device__ __forceinline__ float tanh_f(float x) {
  return 1.f - 2.f * __builtin_amdgcn_rcpf(1.f + __expf(2.f * x));
}
// Extract bf16 payload pair from one tagged u64 (units 2i, 2i+1).
__device__ __forceinline__ unsigned pk(u64 w) {
  return (unsigned)((w >> 16) & 0xFFFFu) | (unsigned)((w >> 48) << 16);
}
#define TAGMASK 0x0000FFFF0000FFFFULL

// ---------------------------------------------------------------------------
__global__ void embed_kernel(const int* __restrict__ tokens,
                             const float* __restrict__ values,
                             const float* __restrict__ emb,
                             __hip_bfloat16* __restrict__ x_bf) {
  int idx = blockIdx.x * blockDim.x + threadIdx.x;   // [0, B*T*E)
  int e  = idx & (E_ - 1);
  int bt = idx >> 7;
  int b  = bt >> 9;
  int t  = bt & (T_ - 1);
  const int*   tok = tokens + (size_t)bt * L_;
  const float* val = values + (size_t)bt * L_;
  float acc = 0.f;
#pragma unroll
  for (int l = 0; l < L_; ++l) acc += emb[(size_t)tok[l] * E_ + e] * val[l];
  acc = fmaxf(acc, 0.f);
  x_bf[((size_t)t * B_ + b) * E_ + e] = __float2bfloat16(acc);
}

// ---------------------------------------------------------------------------
// out[b,t] = W_out . h_t + b_out from the LDS-staged (xor-swizzled) slab.
__device__ __forceinline__ void out_dot_lds(const u64* __restrict__ h_lds,
                                            int t, int bg,
                                            const float* __restrict__ wout_s,
                                            float bout, float* __restrict__ out) {
  const int um = threadIdx.x >> 3;
  const int uj = threadIdx.x & 7;
  const u64* row = h_lds + (size_t)um * 128;
  const float* wr = wout_s + uj * 64;
  float p = 0.f;
#pragma unroll
  for (int j = 0; j < 8; ++j) {
    int pc = ((uj * 8 + j) ^ (um & 7)) * 2;
    u64 qa = row[pc], qb = row[pc + 1];
    p += bf16u_to_f((unsigned short)(qa      )) * wr[j * 8 + 0];
    p += bf16u_to_f((unsigned short)(qa >> 16)) * wr[j * 8 + 1];
    p += bf16u_to_f((unsigned short)(qa >> 32)) * wr[j * 8 + 2];
    p += bf16u_to_f((unsigned short)(qa >> 48)) * wr[j * 8 + 3];
    p += bf16u_to_f((unsigned short)(qb      )) * wr[j * 8 + 4];
    p += bf16u_to_f((unsigned short)(qb >> 16)) * wr[j * 8 + 5];
    p += bf16u_to_f((unsigned short)(qb >> 32)) * wr[j * 8 + 6];
    p += bf16u_to_f((unsigned short)(qb >> 48)) * wr[j * 8 + 7];
  }
  p += __shfl_down(p, 4, 8);
  p += __shfl_down(p, 2, 8);
  p += __shfl_down(p, 1, 8);
  if (uj == 0) out[(size_t)(bg * 32 + um) * T_ + t] = p + bout;
}

// Final-step variant: tagged read of h_{T-1} from global (poll till tag==T).
__device__ __forceinline__ void out_dot_glb_tagged(const u64* __restrict__ slot,
                                                   int t, int bg, unsigned tag,
                                                   const float* __restrict__ wout_s,
                                                   float bout, float* __restrict__ out) {
  const int um = threadIdx.x >> 3;
  const int uj = threadIdx.x & 7;
  const int b  = bg * 32 + um;
  const u64* hr = slot + (size_t)b * 256 + uj * 32;   // 32 u64 = 64 units
  const u64 tagpair = (u64)tag | ((u64)tag << 32);
  u64 w[32];
  for (;;) {
#pragma unroll
    for (int i = 0; i < 32; ++i) w[i] = llc_load8(hr + i);
    u64 bad = 0;
#pragma unroll
    for (int i = 0; i < 32; ++i) bad |= (w[i] & TAGMASK) ^ tagpair;
    if (bad == 0) break;
  }
  const float* wr = wout_s + uj * 64;
  float p = 0.f;
#pragma unroll
  for (int i = 0; i < 32; ++i) {
    p += bf16u_to_f((unsigned short)(w[i] >> 16)) * wr[2 * i];
    p += bf16u_to_f((unsigned short)(w[i] >> 48)) * wr[2 * i + 1];
  }
  p += __shfl_down(p, 4, 8);
  p += __shfl_down(p, 2, 8);
  p += __shfl_down(p, 1, 8);
  if (uj == 0) out[(size_t)b * T_ + t] = p + bout;
}

// ---------------------------------------------------------------------------
__global__ void __launch_bounds__(256, 1)
lstm_kernel(const float* __restrict__ W_ih, const float* __restrict__ W_hh,
            const float* __restrict__ b_ih, const float* __restrict__ b_hh,
            const float* __restrict__ W_out, const float* __restrict__ b_out,
            const __hip_bfloat16* __restrict__ x_bf,
            u64* __restrict__ h_base,             // 3 tagged slots (zeroed)
            float* __restrict__ out) {            // B*T f32
  __shared__ __align__(16) u64   h_lds[32 * 128];  // payload slab, xor-swizzled
  __shared__ __align__(16) float gbuf[32][GSTR];   // gates staging
  __shared__ __align__(16) float bias_s[128];
  __shared__ float wout_s[H_];

  const int tid = threadIdx.x;
  const int wg  = blockIdx.x;
  const int bg  = wg >> 4;            // 0..3
  const int g   = wg & (WPG_ - 1);    // 0..15
  const int j0g = g * JW_;

  const int wv   = tid >> 6;          // wave = gate type 0..3
  const int lane = tid & 63;
  const int m16  = lane & 15;
  const int q    = lane >> 4;
  const int sw   = m16 & 7;           // xor-swizzle key

  // ---- one-time: W fragments -> registers (B operand, 2 N-tiles x 20 K) --
  s8v bfrag[2][20];
#pragma unroll
  for (int nt = 0; nt < 2; ++nt) {
    const int r = wv * H_ + j0g + nt * 16 + m16;        // global gate row
    const float* wih_r = W_ih + (size_t)r * E_;
    const float* whh_r = W_hh + (size_t)r * H_;
#pragma unroll
    for (int ks = 0; ks < 20; ++ks) {
      s8v v;
#pragma unroll
      for (int i = 0; i < 8; ++i) {
        int k = ks * 32 + q * 8 + i;
        float w = (k < E_) ? wih_r[k] : whh_r[k - E_];
        __hip_bfloat16 hb = __float2bfloat16(w);
        v[i] = *(short*)&hb;
      }
      bfrag[nt][ks] = v;
    }
  }
  if (tid < 128) {
    int gt = tid >> 5, jl = tid & 31;
    int r = gt * H_ + j0g + jl;
    bias_s[tid] = b_ih[r] + b_hh[r];
  }
  if (g == 0) for (int i = tid; i < H_; i += 256) wout_s[i] = W_out[i];

  // ---- per-step identities ----------------------------------------------
  const int um = tid >> 3;            // fill/update/out row (0..31)
  const int jb = (tid & 7) * 4;       // update: 4 hidden units
  const int ub = bg * 32 + um;
  const int fc = tid & 7;             // fill: chunk base
  float cst[4] = {0.f, 0.f, 0.f, 0.f};
  const float bout = b_out[0];

  int rp = 2, wp = 0;                 // h_{-1}=zeros(tag 0) in slot2
  f4v acc[2][2];

  // prologue: x-part of step 0
  {
    const __hip_bfloat16* ax0 = x_bf + (size_t)(bg * 32 + m16) * E_ + q * 8;
    const __hip_bfloat16* ax1 = x_bf + (size_t)(bg * 32 + 16 + m16) * E_ + q * 8;
    f4v z = {0.f, 0.f, 0.f, 0.f};
    acc[0][0] = z; acc[0][1] = z; acc[1][0] = z; acc[1][1] = z;
#pragma unroll
    for (int ks = 0; ks < 4; ++ks) {
      s8v a0 = *(const s8v*)(ax0 + ks * 32);
      s8v a1 = *(const s8v*)(ax1 + ks * 32);
#pragma unroll
      for (int nt = 0; nt < 2; ++nt) {
        acc[0][nt] = __builtin_amdgcn_mfma_f32_16x16x32_bf16(a0, bfrag[nt][ks], acc[0][nt], 0, 0, 0);
        acc[1][nt] = __builtin_amdgcn_mfma_f32_16x16x32_bf16(a1, bfrag[nt][ks], acc[1][nt], 0, 0, 0);
      }
    }
  }
  __syncthreads();   // bias/wout ready

  for (int t = 0; t < T_; ++t) {
    const u64* h_prev = h_base + (size_t)rp * SLOTQ;
    u64*       h_next = h_base + (size_t)wp * SLOTQ;

    // ---- tagged fill: poll-load h_{t-1} (tag==t) -> LDS (xor-swizzled) --
    {
      const u64* src = h_prev + (size_t)(bg * 32 + um) * 256;  // 256 u64/row
      const u64 tagpair = (u64)(unsigned)t | ((u64)(unsigned)t << 32);
      u64 w[32];
      for (;;) {
#pragma unroll
        for (int j = 0; j < 8; ++j) {
          int cb = (fc + 8 * j) * 4;           // 4 u64 per 8-unit chunk
          w[4 * j]     = llc_load8(src + cb);
          w[4 * j + 1] = llc_load8(src + cb + 1);
          w[4 * j + 2] = llc_load8(src + cb + 2);
          w[4 * j + 3] = llc_load8(src + cb + 3);
        }
        u64 bad = 0;
#pragma unroll
        for (int i = 0; i < 32; ++i) bad |= (w[i] & TAGMASK) ^ tagpair;
        if (bad == 0) break;
      }
      u64* dst = h_lds + (size_t)um * 128;
#pragma unroll
      for (int j = 0; j < 8; ++j) {
        int pc = ((fc + 8 * j) ^ (um & 7)) * 2;
        dst[pc]     = (u64)pk(w[4 * j])     | ((u64)pk(w[4 * j + 1]) << 32);
        dst[pc + 1] = (u64)pk(w[4 * j + 2]) | ((u64)pk(w[4 * j + 3]) << 32);
      }
    }
    __syncthreads();   // fill complete

    // ---- h-part MFMAs (K=512 from LDS; B from registers) ----------------
    {
      const u64* al0 = h_lds + (size_t)m16 * 128;
      const u64* al1 = h_lds + (size_t)(16 + m16) * 128;
#pragma unroll
      for (int ks4 = 0; ks4 < 16; ++ks4) {
        int pc = ((ks4 * 4 + q) ^ sw) * 2;
        s8v a0 = *(const s8v*)(al0 + pc);
        s8v a1 = *(const s8v*)(al1 + pc);
#pragma unroll
        for (int nt = 0; nt < 2; ++nt) {
          acc[0][nt] = __builtin_amdgcn_mfma_f32_16x16x32_bf16(a0, bfrag[nt][4 + ks4], acc[0][nt], 0, 0, 0);
          acc[1][nt] = __builtin_amdgcn_mfma_f32_16x16x32_bf16(a1, bfrag[nt][4 + ks4], acc[1][nt], 0, 0, 0);
        }
      }
    }

    // ---- stage gates to LDS (D: row=quad*4+r, col=m16) ------------------
#pragma unroll
    for (int mt = 0; mt < 2; ++mt)
#pragma unroll
      for (int nt = 0; nt < 2; ++nt)
#pragma unroll
        for (int r = 0; r < 4; ++r)
          gbuf[mt * 16 + q * 4 + r][wv * 32 + nt * 16 + m16] = acc[mt][nt][r];
    __syncthreads();   // gates ready

    // ---- CRITICAL PATH: pointwise -> tagged h store (no drain, no flag) -
    {
      const float* gr = &gbuf[0][0] + (size_t)um * GSTR;
      f4v vi = *(const f4v*)(gr + jb);
      f4v vf = *(const f4v*)(gr + 32 + jb);
      f4v vg = *(const f4v*)(gr + 64 + jb);
      f4v vo = *(const f4v*)(gr + 96 + jb);
      f4v bi = *(const f4v*)(bias_s + jb);
      f4v bf = *(const f4v*)(bias_s + 32 + jb);
      f4v bgc = *(const f4v*)(bias_s + 64 + jb);
      f4v bo = *(const f4v*)(bias_s + 96 + jb);
      const u64 tagp = (u64)(unsigned)(t + 1);
      unsigned short hb[4];
#pragma unroll
      for (int qq = 0; qq < 4; ++qq) {
        float si = sigf(vi[qq] + bi[qq]);
        float sf = sigf(vf[qq] + bf[qq]);
        float tg = tanh_f(vg[qq] + bgc[qq]);
        float so = sigf(vo[qq] + bo[qq]);
        cst[qq] = sf * cst[qq] + si * tg;
        float h = so * tanh_f(cst[qq]);
        __hip_bfloat16 hx = __float2bfloat16(h);
        hb[qq] = *(unsigned short*)&hx;
      }
      u64 s0 = tagp | ((u64)hb[0] << 16) | (tagp << 32) | ((u64)hb[1] << 48);
      u64 s1 = tagp | ((u64)hb[2] << 16) | (tagp << 32) | ((u64)hb[3] << 48);
      u64* dstp = h_next + (size_t)ub * 256 + ((j0g + jb) >> 1);
      llc_store8(dstp, s0);
      llc_store8(dstp + 1, s1);
    }

    // ---- shadow work (consumers of our h are polling; no rush) ----------
    if (g == 0 && t > 0)               // h_{t-1} still staged in LDS
      out_dot_lds(h_lds, t - 1, bg, wout_s, bout, out);

    if (t + 1 < T_) {                  // x-part of step t+1
      const __hip_bfloat16* xt = x_bf + (size_t)(t + 1) * B_ * E_;
      const __hip_bfloat16* ax0 = xt + (size_t)(bg * 32 + m16) * E_ + q * 8;
      const __hip_bfloat16* ax1 = xt + (size_t)(bg * 32 + 16 + m16) * E_ + q * 8;
      f4v z = {0.f, 0.f, 0.f, 0.f};
      acc[0][0] = z; acc[0][1] = z; acc[1][0] = z; acc[1][1] = z;
#pragma unroll
      for (int ks = 0; ks < 4; ++ks) {
        s8v a0 = *(const s8v*)(ax0 + ks * 32);
        s8v a1 = *(const s8v*)(ax1 + ks * 32);
#pragma unroll
        for (int nt = 0; nt < 2; ++nt) {
          acc[0][nt] = __builtin_amdgcn_mfma_f32_16x16x32_bf16(a0, bfrag[nt][ks], acc[0][nt], 0, 0, 0);
          acc[1][nt] = __builtin_amdgcn_mfma_f32_16x16x32_bf16(a1, bfrag[nt][ks], acc[1][nt], 0, 0, 0);
        }
      }
    }

    __syncthreads();   // protect h_lds (shadow reads) before next fill

    rp = wp; wp = (wp == 2) ? 0 : wp + 1;
  }

  // final output row: h_{T-1} (tag T_) from slot rp
  if (g == 0)
    out_dot_glb_tagged(h_base + (size_t)rp * SLOTQ, T_ - 1, bg, (unsigned)T_,
                       wout_s, bout, out);
}

// ---------------------------------------------------------------------------
extern "C" void kernel_launch(void* const* d_in, const int* in_sizes, int n_in,
                              void* d_out, int out_size, void* d_ws, size_t ws_size,
                              hipStream_t stream) {
  const int*   tokens = (const int*)d_in[0];
  const float* values = (const float*)d_in[1];
  const float* emb    = (const float*)d_in[2];
  const float* W_ih   = (const float*)d_in[3];
  const float* W_hh   = (const float*)d_in[4];
  const float* b_ih   = (const float*)d_in[5];
  const float* b_hh   = (const float*)d_in[6];
  const float* W_out  = (const float*)d_in[7];
  const float* b_out  = (const float*)d_in[8];
  float* out = (float*)d_out;

  char* ws = (char*)d_ws;
  __hip_bfloat16* x_bf = (__hip_bfloat16*)ws;                         // 16 MB
  u64* h_base = (u64*)(ws + (size_t)T_ * B_ * E_ * 2);                // 3 x 256KB

  // zero all 3 tagged slots: tag 0 == expected tag at t=0 (h_{-1} = 0)
  hipMemsetAsync(h_base, 0, (size_t)3 * SLOTQ * sizeof(u64), stream);

  embed_kernel<<<(B_ * T_ * E_) / 256, 256, 0, stream>>>(tokens, values, emb, x_bf);

  lstm_kernel<<<dim3(BG_ * WPG_), dim3(256), 0, stream>>>(
      W_ih, W_hh, b_ih, b_hh, W_out, b_out, x_bf, h_base, out);
}